// Round 8
// baseline (415.174 us; speedup 1.0000x reference)
//
#include <hip/hip_runtime.h>
#include <hip/hip_cooperative_groups.h>

#define HIDDEN 256
#define CAP 64   // bucket capacity per node; deg ~ Poisson(16) => P(deg>=64) ~ e^-40

namespace cg = cooperative_groups;

typedef _Float16 h4_t __attribute__((ext_vector_type(4)));
typedef _Float16 h8_t __attribute__((ext_vector_type(8)));
typedef float    f4_t __attribute__((ext_vector_type(4)));

typedef const __attribute__((address_space(1))) void* gbl_ptr_t;
typedef __attribute__((address_space(3))) void*       lds_ptr_t;

__device__ inline f4_t cvt4(h4_t h) {
    f4_t o; o.x = (float)h.x; o.y = (float)h.y; o.z = (float)h.z; o.w = (float)h.w;
    return o;
}

// ---------------- m97-structure GEMM tile (R6-verified), as a device function --------
// 128x128 tile, 4 waves, BK=32, 16 KB LDS, two barriers/K-step, next-step staging
// overlaps MFMAs. R7 probe: trio costs ~40us total in-pipeline.
template <int K, bool RELU, bool HAS_BIAS, bool OUT_F16, bool MASK>
__device__ __forceinline__ void gemm_tile(
        _Float16* As, _Float16* Bs,
        const _Float16* A, const _Float16* B,
        const float* bias, void* Cout,
        const unsigned char* flags, int Mstore, int N, int m0, int n0) {
    int t = threadIdx.x;
    int w = t >> 6, L = t & 63;
    int wr = (w >> 1) * 64, wc = (w & 1) * 64;        // wave quadrant origin in tile
    int lr = L & 15, lk = (L >> 4) * 8;

    f4_t acc[4][4] = {};

    auto stage = [&](int k0) {
#pragma unroll
        for (int i = 0; i < 2; ++i) {                 // A: 512 16B chunks / 256 thr
            int c = t + 256 * i;
            __builtin_amdgcn_global_load_lds(
                (gbl_ptr_t)(A + (size_t)(m0 + (c >> 2)) * K + k0 + (c & 3) * 8),
                (lds_ptr_t)(As + c * 8), 16, 0, 0);
        }
#pragma unroll
        for (int i = 0; i < 2; ++i) {                 // B: 512 chunks
            int c = t + 256 * i;
            __builtin_amdgcn_global_load_lds(
                (gbl_ptr_t)(B + (size_t)(n0 + (c >> 2)) * K + k0 + (c & 3) * 8),
                (lds_ptr_t)(Bs + c * 8), 16, 0, 0);
        }
    };

    stage(0);
    constexpr int NS = K / 32;
#pragma unroll
    for (int s = 0; s < NS; ++s) {
        asm volatile("s_waitcnt vmcnt(0)" ::: "memory");   // own staging landed
        __syncthreads();                                   // ALL waves' staging landed
        h8_t af[4], bf[4];
#pragma unroll
        for (int i = 0; i < 4; ++i) af[i] = *(const h8_t*)&As[(wr + i * 16 + lr) * 32 + lk];
#pragma unroll
        for (int j = 0; j < 4; ++j) bf[j] = *(const h8_t*)&Bs[(wc + j * 16 + lr) * 32 + lk];
        asm volatile("s_waitcnt lgkmcnt(0)" ::: "memory"); // frags in regs
        __syncthreads();                                   // all waves done reading LDS
        if (s + 1 < NS) stage((s + 1) * 32);               // overlaps MFMAs below
#pragma unroll
        for (int i = 0; i < 4; ++i)
#pragma unroll
            for (int j = 0; j < 4; ++j)
                acc[i][j] = __builtin_amdgcn_mfma_f32_16x16x32_f16(af[i], bf[j], acc[i][j], 0, 0, 0);
    }

    // epilogue: C/D layout col = L&15, row = (L>>4)*4 + r
    int lr4 = (L >> 4) * 4;
#pragma unroll
    for (int i = 0; i < 4; ++i)
#pragma unroll
        for (int r = 0; r < 4; ++r) {
            int row = m0 + wr + i * 16 + lr4 + r;
            float zm = 1.f;
            if constexpr (MASK) zm = flags[row] ? 0.f : 1.f;
#pragma unroll
            for (int j = 0; j < 4; ++j) {
                int col = n0 + wc + j * 16 + lr;
                float v = acc[i][j][r];
                if constexpr (HAS_BIAS) v += bias[col];
                if constexpr (RELU) v = v > 0.f ? v : 0.f;
                v *= zm;
                if constexpr (OUT_F16) {
                    ((_Float16*)Cout)[(size_t)row * N + col] = (_Float16)v;
                } else {
                    if (row < Mstore) ((float*)Cout)[(size_t)row * N + col] = v;
                }
            }
        }
}

// ---------------- mega-kernel params ----------------
struct KP {
    const float* x; const int* ei; const int* ea; const int* mask;
    const float* prelu_a;
    const float* W_enc; const float* E1; const float* E2;
    const float* W1; const float* b1; const float* W2; const float* b2;
    float* out;
    _Float16 *xh, *XEh, *AGh, *Hh, *Whenc, *Wh1, *Wh2;
    int* cnt; unsigned char* flags; int* csr;
    int N, E, NM, Mpad;
};

// ---------------- single cooperative mega-kernel: all 6 pipeline nodes ---------------
// R7 analysis: kernel work ~86-96us vs dur 178.6us -> ~80us is poison-fill floor +
// 5 serialized launch gaps. This removes the gaps: phases separated by grid.sync().
// __launch_bounds__(256,3) caps VGPR<=170 (GEMM3 needs 144) -> 3 blocks/CU
// guaranteed co-resident; grid = occupancy*256 CUs. Cost accepted: aggregate phase
// runs at ~12 waves/CU instead of ~21 (est +5-10us on a 29us phase).
__global__ __launch_bounds__(256, 3) void k_mega(KP p) {
    __shared__ __align__(16) char smem[16384];     // union: GEMM As+Bs / aggregate e12h
    _Float16* As = (_Float16*)smem;
    _Float16* Bs = (_Float16*)(smem + 8192);
    cg::grid_group gg = cg::this_grid();
    const int b = blockIdx.x, t = threadIdx.x, G = gridDim.x;

    // ---- P0: zero cnt + flags (replaces hipMemsetAsync node) ----
    for (int i = b * 256 + t; i < p.N;    i += G * 256) p.cnt[i] = 0;
    for (int i = b * 256 + t; i < p.Mpad; i += G * 256) p.flags[i] = 0;
    gg.sync();

    // ---- P1: prep (x->f16 prelu, bucket-fill, weights->f16, mask flags) ----
    {
        const int nb_x    = p.Mpad * (HIDDEN / 4) / 256;                // 5024, exact
        const int nb_fill = (p.E + 255) / 256;                          // 1250
        const int wtot4   = (HIDDEN*HIDDEN + 2*HIDDEN*HIDDEN + HIDDEN*2*HIDDEN) / 4;
        const int nb_w    = (wtot4 + 255) / 256;                        // 320, exact
        const int nb_m    = (p.NM + 255) / 256;                         // 8
        const int nbtot   = nb_x + nb_fill + nb_w + nb_m;
        float pa = *p.prelu_a;
        for (int u = b; u < nbtot; u += G) {
            if (u < nb_x) {
                int base = (u * 256 + t) * 4;
                int row = base >> 8;
                h4_t o;
                if (row < p.N) {
                    f4_t v = *(const f4_t*)(p.x + base);
                    o.x = (_Float16)(v.x >= 0.f ? v.x : pa * v.x);
                    o.y = (_Float16)(v.y >= 0.f ? v.y : pa * v.y);
                    o.z = (_Float16)(v.z >= 0.f ? v.z : pa * v.z);
                    o.w = (_Float16)(v.w >= 0.f ? v.w : pa * v.w);
                } else {
                    o = (h4_t)(_Float16)0.f;
                }
                *(h4_t*)(p.xh + base) = o;
            } else if (u < nb_x + nb_fill) {
                int e = (u - nb_x) * 256 + t;
                if (e < p.E) {
                    int src = p.ei[e];
                    int dst = p.ei[p.E + e];
                    int combo = p.ea[2 * e] * 3 + p.ea[2 * e + 1];
                    int slot = atomicAdd(&p.cnt[dst], 1);
                    if (slot < CAP) p.csr[dst * CAP + slot] = src | (combo << 16);
                }
            } else if (u < nb_x + nb_fill + nb_w) {
                const int n0w = HIDDEN*HIDDEN, n1w = 2*HIDDEN*HIDDEN, n2w = HIDDEN*2*HIDDEN;
                int base = ((u - nb_x - nb_fill) * 256 + t) * 4;
                const float* s; _Float16* d; int off;
                if (base < n0w)             { s = p.W_enc; d = p.Whenc; off = base; }
                else if (base < n0w + n1w)  { s = p.W1;    d = p.Wh1;   off = base - n0w; }
                else                        { s = p.W2;    d = p.Wh2;   off = base - n0w - n1w; }
                f4_t v = *(const f4_t*)(s + off);
                h4_t o; o.x = (_Float16)v.x; o.y = (_Float16)v.y;
                o.z = (_Float16)v.z; o.w = (_Float16)v.w;
                *(h4_t*)(d + off) = o;
            } else {
                int i = (u - nb_x - nb_fill - nb_w) * 256 + t;
                if (i < p.NM) p.flags[p.mask[i]] = 1;
            }
        }
    }
    gg.sync();

    // ---- P2: GEMM1  XE = (prelu(x)@W_enc^T), masked rows zeroed ----
    {
        const int nbx = HIDDEN / 128;                 // 2
        const int ntiles = nbx * (p.Mpad / 128);      // 314
        for (int T = b; T < ntiles; T += G)
            gemm_tile<HIDDEN, false, false, true, true>(
                As, Bs, p.xh, p.Whenc, nullptr, p.XEh, p.flags, p.N, HIDDEN,
                (T / nbx) * 128, (T % nbx) * 128);
    }
    gg.sync();

    // ---- P3: aggregate (R5-verified gather; e12h rebuilt in the LDS union) ----
    {
        _Float16* e12h = (_Float16*)smem;             // 9 KB
        for (int idx = t; idx < 18 * 64; idx += 256) {
            int combo = idx >> 6, c4 = (idx & 63) * 4;
            int a1 = combo / 3, a2 = combo - a1 * 3;
            f4_t v1 = *(const f4_t*)(p.E1 + a1 * HIDDEN + c4);
            f4_t v2 = *(const f4_t*)(p.E2 + a2 * HIDDEN + c4);
            h4_t o;
            o.x = (_Float16)(v1.x + v2.x); o.y = (_Float16)(v1.y + v2.y);
            o.z = (_Float16)(v1.z + v2.z); o.w = (_Float16)(v1.w + v2.w);
            *(h4_t*)(e12h + combo * HIDDEN + c4) = o;
        }
        __syncthreads();
        int w = t >> 6, lane = t & 63, c0 = lane * 4;
        int ngr = p.Mpad / 4;
        for (int g = b; g < ngr; g += G) {
            int node = g * 4 + w;                     // uniform per wave
            if (node >= p.N) {
                *(h4_t*)(p.AGh + (size_t)node * HIDDEN + c0) = (h4_t)(_Float16)0.f;
                continue;
            }
            int deg = p.cnt[node];
            if (deg > CAP) deg = CAP;
            const int* lst = p.csr + (size_t)node * CAP;
            int pv = (lane < deg) ? lst[lane] : 0;

            h4_t hs = *(const h4_t*)(p.XEh + (size_t)node * HIDDEN + c0);
            h4_t se = *(const h4_t*)(e12h + 12 * HIDDEN + c0);   // E1[4]+E2[0]
            f4_t acc = cvt4(hs) + cvt4(se);

            int e = 0;
            for (; e + 7 < deg; e += 8) {
                int pp[8]; h4_t hv[8], qv[8];
#pragma unroll
                for (int j = 0; j < 8; ++j) pp[j] = __shfl(pv, e + j, 64);
#pragma unroll
                for (int j = 0; j < 8; ++j)
                    hv[j] = *(const h4_t*)(p.XEh + (size_t)(pp[j] & 0xFFFF) * HIDDEN + c0);
#pragma unroll
                for (int j = 0; j < 8; ++j)
                    qv[j] = *(const h4_t*)(e12h + (pp[j] >> 16) * HIDDEN + c0);
                h4_t s0 = (hv[0] + qv[0]) + (hv[1] + qv[1]);
                h4_t s1 = (hv[2] + qv[2]) + (hv[3] + qv[3]);
                h4_t s2 = (hv[4] + qv[4]) + (hv[5] + qv[5]);
                h4_t s3 = (hv[6] + qv[6]) + (hv[7] + qv[7]);
                acc += cvt4(s0) + cvt4(s1);
                acc += cvt4(s2) + cvt4(s3);
            }
            for (; e < deg; ++e) {
                int pe = __shfl(pv, e, 64);
                h4_t h = *(const h4_t*)(p.XEh + (size_t)(pe & 0xFFFF) * HIDDEN + c0);
                h4_t q = *(const h4_t*)(e12h + (pe >> 16) * HIDDEN + c0);
                acc += cvt4(h + q);
            }
            h4_t o;
            o.x = (_Float16)acc.x; o.y = (_Float16)acc.y;
            o.z = (_Float16)acc.z; o.w = (_Float16)acc.w;
            *(h4_t*)(p.AGh + (size_t)node * HIDDEN + c0) = o;
        }
    }
    gg.sync();

    // ---- P4: GEMM2  H = relu(AG@W1^T + b1) ----
    {
        const int nbx = 2 * HIDDEN / 128;             // 4
        const int ntiles = nbx * (p.Mpad / 128);      // 628
        for (int T = b; T < ntiles; T += G)
            gemm_tile<HIDDEN, true, true, true, false>(
                As, Bs, p.AGh, p.Wh1, p.b1, p.Hh, nullptr, p.N, 2 * HIDDEN,
                (T / nbx) * 128, (T % nbx) * 128);
    }
    gg.sync();

    // ---- P5: GEMM3  out = H@W2^T + b2 (f32) ----
    {
        const int nbx = HIDDEN / 128;                 // 2
        const int ntiles = nbx * (p.Mpad / 128);      // 314
        for (int T = b; T < ntiles; T += G)
            gemm_tile<2 * HIDDEN, false, true, false, false>(
                As, Bs, p.Hh, p.Wh2, p.b2, p.out, nullptr, p.N, HIDDEN,
                (T / nbx) * 128, (T % nbx) * 128);
    }
}

// ================= fallback path (exact R6 pipeline) if cooperative enqueue fails ====
__global__ __launch_bounds__(256) void k_prep(
        const float* __restrict__ x, _Float16* __restrict__ xh,
        const float* __restrict__ prelu_a, int M, int Mpad, int nb_x,
        const int* __restrict__ ei, const int* __restrict__ ea, int E,
        int* __restrict__ cnt, int* __restrict__ csr, int nb_fill,
        const float* __restrict__ W_enc, const float* __restrict__ W1,
        const float* __restrict__ W2, _Float16* __restrict__ Whenc,
        _Float16* __restrict__ Wh1, _Float16* __restrict__ Wh2, int nb_w,
        const int* __restrict__ mask, unsigned char* __restrict__ flags, int NM) {
    int b = blockIdx.x;
    int t = threadIdx.x;
    if (b < nb_x) {
        int base = (b * 256 + t) * 4;
        if (base >= Mpad * HIDDEN) return;
        int row = base >> 8;
        h4_t o;
        if (row < M) {
            float pa = *prelu_a;
            f4_t v = *(const f4_t*)(x + base);
            o.x = (_Float16)(v.x >= 0.f ? v.x : pa * v.x);
            o.y = (_Float16)(v.y >= 0.f ? v.y : pa * v.y);
            o.z = (_Float16)(v.z >= 0.f ? v.z : pa * v.z);
            o.w = (_Float16)(v.w >= 0.f ? v.w : pa * v.w);
        } else {
            o = (h4_t)(_Float16)0.f;
        }
        *(h4_t*)(xh + base) = o;
        return;
    }
    b -= nb_x;
    if (b < nb_fill) {
        int e = b * 256 + t;
        if (e >= E) return;
        int src = ei[e];
        int dst = ei[E + e];
        int combo = ea[2 * e] * 3 + ea[2 * e + 1];
        int slot = atomicAdd(&cnt[dst], 1);
        if (slot < CAP) csr[dst * CAP + slot] = src | (combo << 16);
        return;
    }
    b -= nb_fill;
    if (b < nb_w) {
        const int n0 = HIDDEN * HIDDEN, n1 = 2 * HIDDEN * HIDDEN, n2 = HIDDEN * 2 * HIDDEN;
        int base = (b * 256 + t) * 4;
        const float* s; _Float16* d; int off;
        if (base < n0) { s = W_enc; d = Whenc; off = base; }
        else if (base < n0 + n1) { s = W1; d = Wh1; off = base - n0; }
        else if (base < n0 + n1 + n2) { s = W2; d = Wh2; off = base - n0 - n1; }
        else return;
        f4_t v = *(const f4_t*)(s + off);
        h4_t o; o.x = (_Float16)v.x; o.y = (_Float16)v.y;
        o.z = (_Float16)v.z; o.w = (_Float16)v.w;
        *(h4_t*)(d + off) = o;
        return;
    }
    b -= nb_w;
    {
        int i = b * 256 + t;
        if (i < NM) flags[mask[i]] = 1;
    }
}

__global__ __launch_bounds__(256) void k_aggregate(
        const _Float16* __restrict__ xe,
        const float* __restrict__ E1, const float* __restrict__ E2,
        const int* __restrict__ cnt, const int* __restrict__ csr,
        _Float16* __restrict__ aggr, int N, int Mpad) {
    __shared__ __align__(16) _Float16 e12h[18 * HIDDEN];
    int t = threadIdx.x;
    for (int idx = t; idx < 18 * 64; idx += 256) {
        int combo = idx >> 6, c4 = (idx & 63) * 4;
        int a1 = combo / 3, a2 = combo - a1 * 3;
        f4_t v1 = *(const f4_t*)(E1 + a1 * HIDDEN + c4);
        f4_t v2 = *(const f4_t*)(E2 + a2 * HIDDEN + c4);
        h4_t o;
        o.x = (_Float16)(v1.x + v2.x); o.y = (_Float16)(v1.y + v2.y);
        o.z = (_Float16)(v1.z + v2.z); o.w = (_Float16)(v1.w + v2.w);
        *(h4_t*)(e12h + combo * HIDDEN + c4) = o;
    }
    __syncthreads();
    int node = blockIdx.x * 4 + (t >> 6);
    if (node >= Mpad) return;
    int lane = t & 63;
    int c0 = lane * 4;
    if (node >= N) {
        *(h4_t*)(aggr + (size_t)node * HIDDEN + c0) = (h4_t)(_Float16)0.f;
        return;
    }
    int deg = cnt[node];
    if (deg > CAP) deg = CAP;
    const int* lst = csr + (size_t)node * CAP;
    int pv = (lane < deg) ? lst[lane] : 0;

    h4_t hs = *(const h4_t*)(xe + (size_t)node * HIDDEN + c0);
    h4_t se = *(const h4_t*)(e12h + 12 * HIDDEN + c0);
    f4_t acc = cvt4(hs) + cvt4(se);

    int e = 0;
    for (; e + 7 < deg; e += 8) {
        int pp[8]; h4_t hv[8], qv[8];
#pragma unroll
        for (int j = 0; j < 8; ++j) pp[j] = __shfl(pv, e + j, 64);
#pragma unroll
        for (int j = 0; j < 8; ++j)
            hv[j] = *(const h4_t*)(xe + (size_t)(pp[j] & 0xFFFF) * HIDDEN + c0);
#pragma unroll
        for (int j = 0; j < 8; ++j)
            qv[j] = *(const h4_t*)(e12h + (pp[j] >> 16) * HIDDEN + c0);
        h4_t s0 = (hv[0] + qv[0]) + (hv[1] + qv[1]);
        h4_t s1 = (hv[2] + qv[2]) + (hv[3] + qv[3]);
        h4_t s2 = (hv[4] + qv[4]) + (hv[5] + qv[5]);
        h4_t s3 = (hv[6] + qv[6]) + (hv[7] + qv[7]);
        acc += cvt4(s0) + cvt4(s1);
        acc += cvt4(s2) + cvt4(s3);
    }
    for (; e < deg; ++e) {
        int pe = __shfl(pv, e, 64);
        h4_t h = *(const h4_t*)(xe + (size_t)(pe & 0xFFFF) * HIDDEN + c0);
        h4_t q = *(const h4_t*)(e12h + (pe >> 16) * HIDDEN + c0);
        acc += cvt4(h + q);
    }
    h4_t o;
    o.x = (_Float16)acc.x; o.y = (_Float16)acc.y;
    o.z = (_Float16)acc.z; o.w = (_Float16)acc.w;
    *(h4_t*)(aggr + (size_t)node * HIDDEN + c0) = o;
}

template <int K, bool RELU, bool HAS_BIAS, bool OUT_F16, bool MASK>
__global__ __launch_bounds__(256) void k_gemm128(
        const _Float16* __restrict__ A, const _Float16* __restrict__ B,
        const float* __restrict__ bias, void* __restrict__ Cout,
        const unsigned char* __restrict__ flags, int Mstore, int N) {
    __shared__ __align__(16) char smem[16384];
    gemm_tile<K, RELU, HAS_BIAS, OUT_F16, MASK>(
        (_Float16*)smem, (_Float16*)(smem + 8192),
        A, B, bias, Cout, flags, Mstore, N, blockIdx.y * 128, blockIdx.x * 128);
}

extern "C" void kernel_launch(void* const* d_in, const int* in_sizes, int n_in,
                              void* d_out, int out_size, void* d_ws, size_t ws_size,
                              hipStream_t stream) {
    const float* x       = (const float*)d_in[0];
    const int*   ei      = (const int*)d_in[1];
    const int*   ea      = (const int*)d_in[2];
    const int*   mask    = (const int*)d_in[3];
    const float* prelu_a = (const float*)d_in[4];
    const float* W_enc   = (const float*)d_in[5];
    const float* E1      = (const float*)d_in[6];
    const float* E2      = (const float*)d_in[7];
    const float* W1      = (const float*)d_in[8];
    const float* b1      = (const float*)d_in[9];
    const float* W2      = (const float*)d_in[10];
    const float* b2      = (const float*)d_in[11];
    float*       out     = (float*)d_out;

    int N  = in_sizes[0] / HIDDEN;           // 20000
    int E  = in_sizes[1] / 2;                // 320000
    int NM = in_sizes[3];                    // 2000
    int Mpad = ((N + 127) / 128) * 128;      // 20096 (multiple of 128)

    char* ws = (char*)d_ws;
    size_t off = 0;
    _Float16* xh    = (_Float16*)(ws + off); off += (size_t)Mpad * HIDDEN * 2;
    _Float16* XEh   = (_Float16*)(ws + off); off += (size_t)Mpad * HIDDEN * 2;
    _Float16* AGh   = (_Float16*)(ws + off); off += (size_t)Mpad * HIDDEN * 2;
    _Float16* Hh    = (_Float16*)(ws + off); off += (size_t)Mpad * 2 * HIDDEN * 2;
    _Float16* Whenc = (_Float16*)(ws + off); off += (size_t)HIDDEN * HIDDEN * 2;
    _Float16* Wh1   = (_Float16*)(ws + off); off += (size_t)2 * HIDDEN * HIDDEN * 2;
    _Float16* Wh2   = (_Float16*)(ws + off); off += (size_t)HIDDEN * 2 * HIDDEN * 2;
    int* cnt        = (int*)(ws + off);      off += (size_t)N * 4;
    unsigned char* flags = (unsigned char*)(ws + off); off += (size_t)Mpad;
    off = (off + 15) & ~(size_t)15;
    int* csr        = (int*)(ws + off);      off += (size_t)N * CAP * 4;

    KP kp{x, ei, ea, mask, prelu_a, W_enc, E1, E2, W1, b1, W2, b2, out,
          xh, XEh, AGh, Hh, Whenc, Wh1, Wh2, cnt, flags, csr, N, E, NM, Mpad};

    int mb = 0;
    hipError_t qerr = hipOccupancyMaxActiveBlocksPerMultiprocessor(&mb, k_mega, 256, 0);
    if (qerr != hipSuccess || mb < 1) mb = 1;
    int grid = mb * 256;                     // 256 CUs on MI355X; all co-resident
    if (grid > 2048) grid = 2048;
    void* args[] = { &kp };
    hipError_t cerr = hipLaunchCooperativeKernel(
        (const void*)k_mega, dim3(grid), dim3(256), args, 0, stream);

    if (cerr != hipSuccess) {
        // -------- fallback: exact R6 6-dispatch pipeline --------
        hipMemsetAsync(cnt, 0, (size_t)N * 4 + (size_t)Mpad, stream);
        int nb_x    = (Mpad * HIDDEN / 4 + 255) / 256;
        int nb_fill = (E + 255) / 256;
        int wtot4   = (HIDDEN * HIDDEN + 2 * HIDDEN * HIDDEN + HIDDEN * 2 * HIDDEN) / 4;
        int nb_w    = (wtot4 + 255) / 256;
        int nb_m    = (NM + 255) / 256;
        k_prep<<<nb_x + nb_fill + nb_w + nb_m, 256, 0, stream>>>(
            x, xh, prelu_a, N, Mpad, nb_x,
            ei, ea, E, cnt, csr, nb_fill,
            W_enc, W1, W2, Whenc, Wh1, Wh2, nb_w,
            mask, flags, NM);
        dim3 g1(HIDDEN / 128, Mpad / 128);
        k_gemm128<HIDDEN, false, false, true, true><<<g1, 256, 0, stream>>>(
            xh, Whenc, nullptr, XEh, flags, N, HIDDEN);
        k_aggregate<<<(Mpad + 3) / 4, 256, 0, stream>>>(XEh, E1, E2, cnt, csr, AGh, N, Mpad);
        dim3 g2(2 * HIDDEN / 128, Mpad / 128);
        k_gemm128<HIDDEN, true, true, true, false><<<g2, 256, 0, stream>>>(
            AGh, Wh1, b1, Hh, nullptr, N, 2 * HIDDEN);
        dim3 g3(HIDDEN / 128, Mpad / 128);
        k_gemm128<2 * HIDDEN, false, true, false, false><<<g3, 256, 0, stream>>>(
            Hh, Wh2, b2, out, nullptr, N, HIDDEN);
    }
}

// Round 9
// 177.644 us; speedup vs baseline: 2.3371x; 2.3371x over previous
//
#include <hip/hip_runtime.h>

#define HIDDEN 256
#define CAP 64   // bucket capacity per node; deg ~ Poisson(16) => P(deg>=64) ~ e^-40

typedef _Float16 h4_t __attribute__((ext_vector_type(4)));
typedef _Float16 h8_t __attribute__((ext_vector_type(8)));
typedef float    f4_t __attribute__((ext_vector_type(4)));

typedef const __attribute__((address_space(1))) void* gbl_ptr_t;
typedef __attribute__((address_space(3))) void*       lds_ptr_t;

__device__ inline f4_t cvt4(h4_t h) {
    f4_t o; o.x = (float)h.x; o.y = (float)h.y; o.z = (float)h.z; o.w = (float)h.w;
    return o;
}

// ---------------- fused prep: x->f16(prelu), weights->f16, bucket-fill, mask flags ----
// (byte-identical to R6)
__global__ __launch_bounds__(256) void k_prep(
        const float* __restrict__ x, _Float16* __restrict__ xh,
        const float* __restrict__ prelu_a, int M, int Mpad, int nb_x,
        const int* __restrict__ ei, const int* __restrict__ ea, int E,
        int* __restrict__ cnt, int* __restrict__ csr, int nb_fill,
        const float* __restrict__ W_enc, const float* __restrict__ W1,
        const float* __restrict__ W2, _Float16* __restrict__ Whenc,
        _Float16* __restrict__ Wh1, _Float16* __restrict__ Wh2, int nb_w,
        const int* __restrict__ mask, unsigned char* __restrict__ flags, int NM) {
    int b = blockIdx.x;
    int t = threadIdx.x;
    if (b < nb_x) {
        int base = (b * 256 + t) * 4;
        if (base >= Mpad * HIDDEN) return;
        int row = base >> 8;
        h4_t o;
        if (row < M) {
            float pa = *prelu_a;
            f4_t v = *(const f4_t*)(x + base);
            o.x = (_Float16)(v.x >= 0.f ? v.x : pa * v.x);
            o.y = (_Float16)(v.y >= 0.f ? v.y : pa * v.y);
            o.z = (_Float16)(v.z >= 0.f ? v.z : pa * v.z);
            o.w = (_Float16)(v.w >= 0.f ? v.w : pa * v.w);
        } else {
            o = (h4_t)(_Float16)0.f;
        }
        *(h4_t*)(xh + base) = o;
        return;
    }
    b -= nb_x;
    if (b < nb_fill) {
        int e = b * 256 + t;
        if (e >= E) return;
        int src = ei[e];
        int dst = ei[E + e];
        int combo = ea[2 * e] * 3 + ea[2 * e + 1];     // a1*3+a2, 0..17
        int slot = atomicAdd(&cnt[dst], 1);
        if (slot < CAP) csr[dst * CAP + slot] = src | (combo << 16);
        return;
    }
    b -= nb_fill;
    if (b < nb_w) {
        const int n0 = HIDDEN * HIDDEN, n1 = 2 * HIDDEN * HIDDEN, n2 = HIDDEN * 2 * HIDDEN;
        int base = (b * 256 + t) * 4;
        const float* s; _Float16* d; int off;
        if (base < n0) { s = W_enc; d = Whenc; off = base; }
        else if (base < n0 + n1) { s = W1; d = Wh1; off = base - n0; }
        else if (base < n0 + n1 + n2) { s = W2; d = Wh2; off = base - n0 - n1; }
        else return;
        f4_t v = *(const f4_t*)(s + off);
        h4_t o; o.x = (_Float16)v.x; o.y = (_Float16)v.y;
        o.z = (_Float16)v.z; o.w = (_Float16)v.w;
        *(h4_t*)(d + off) = o;
        return;
    }
    b -= nb_w;
    {
        int i = b * 256 + t;
        if (i < NM) flags[mask[i]] = 1;
    }
}

// ---------------- aggregation: 4 nodes / 256-thr block; csr preload + 8-wide gather --
// R5 probe: ~29us in-pipeline, VALUBusy 51%, 0 bank conflicts, L3-served gather.
// (byte-identical to R6)
__global__ __launch_bounds__(256) void k_aggregate(
        const _Float16* __restrict__ xe,
        const float* __restrict__ E1, const float* __restrict__ E2,
        const int* __restrict__ cnt, const int* __restrict__ csr,
        _Float16* __restrict__ aggr, int N, int Mpad) {
    __shared__ __align__(16) _Float16 e12h[18 * HIDDEN];   // 9 KB
    int t = threadIdx.x;
    for (int idx = t; idx < 18 * 64; idx += 256) {
        int combo = idx >> 6, c4 = (idx & 63) * 4;
        int a1 = combo / 3, a2 = combo - a1 * 3;
        f4_t v1 = *(const f4_t*)(E1 + a1 * HIDDEN + c4);
        f4_t v2 = *(const f4_t*)(E2 + a2 * HIDDEN + c4);
        h4_t o;
        o.x = (_Float16)(v1.x + v2.x); o.y = (_Float16)(v1.y + v2.y);
        o.z = (_Float16)(v1.z + v2.z); o.w = (_Float16)(v1.w + v2.w);
        *(h4_t*)(e12h + combo * HIDDEN + c4) = o;
    }
    __syncthreads();
    int node = blockIdx.x * 4 + (t >> 6);
    if (node >= Mpad) return;
    int lane = t & 63;
    int c0 = lane * 4;
    if (node >= N) {
        *(h4_t*)(aggr + (size_t)node * HIDDEN + c0) = (h4_t)(_Float16)0.f;
        return;
    }
    int deg = cnt[node];
    if (deg > CAP) deg = CAP;
    const int* lst = csr + (size_t)node * CAP;
    int pv = (lane < deg) ? lst[lane] : 0;        // all edge descriptors, 1 per lane

    h4_t hs = *(const h4_t*)(xe + (size_t)node * HIDDEN + c0);
    h4_t se = *(const h4_t*)(e12h + 12 * HIDDEN + c0);     // self-loop: E1[4]+E2[0]
    f4_t acc = cvt4(hs) + cvt4(se);

    int e = 0;
    for (; e + 7 < deg; e += 8) {
        int p[8]; h4_t hv[8], qv[8];
#pragma unroll
        for (int j = 0; j < 8; ++j) p[j] = __shfl(pv, e + j, 64);
#pragma unroll
        for (int j = 0; j < 8; ++j)
            hv[j] = *(const h4_t*)(xe + (size_t)(p[j] & 0xFFFF) * HIDDEN + c0);
#pragma unroll
        for (int j = 0; j < 8; ++j)
            qv[j] = *(const h4_t*)(e12h + (p[j] >> 16) * HIDDEN + c0);
        h4_t s0 = (hv[0] + qv[0]) + (hv[1] + qv[1]);   // v_pk_add_f16 trees, depth 2
        h4_t s1 = (hv[2] + qv[2]) + (hv[3] + qv[3]);
        h4_t s2 = (hv[4] + qv[4]) + (hv[5] + qv[5]);
        h4_t s3 = (hv[6] + qv[6]) + (hv[7] + qv[7]);
        acc += cvt4(s0) + cvt4(s1);
        acc += cvt4(s2) + cvt4(s3);
    }
    for (; e < deg; ++e) {
        int p = __shfl(pv, e, 64);
        h4_t h = *(const h4_t*)(xe + (size_t)(p & 0xFFFF) * HIDDEN + c0);
        h4_t q = *(const h4_t*)(e12h + (p >> 16) * HIDDEN + c0);
        acc += cvt4(h + q);
    }
    h4_t o;
    o.x = (_Float16)acc.x; o.y = (_Float16)acc.y;
    o.z = (_Float16)acc.z; o.w = (_Float16)acc.w;
    *(h4_t*)(aggr + (size_t)node * HIDDEN + c0) = o;
}

// ---------------- 4-wave 128x128 GEMM, BK=64: C = act(A @ B^T + bias) ----------------
// R7 diagnosis: walls are per-TILE LATENCY (all blocks co-resident; wall = NS x
// (staging latency ~2000cy + ~400cy compute)). BK=64 halves NS (8->4, 16->8):
// per step, stage BOTH 32-wide k-halves (8 global_load_lds/thread), each half in
// the exact R6 [128][32] layout (same banks, same fragment addressing). Compute
// splits into two sub-rounds: frags(h0) -> MFMA(h0) overlapping ds_read(h1) ->
// lgkm+barrier -> stage(next) -> MFMA(h1). Two barriers per step but half the
// steps. LDS 32KB -> 5 blocks/CU LDS-cap; VGPR ~145 -> 3/CU (unchanged vs R6;
// R2's trap was 32KB per 1-WAVE block). Accumulation k-order identical to R6 ->
// bitwise-same output. R8 lesson: no cooperative/persistent forms.
template <int K, bool RELU, bool HAS_BIAS, bool OUT_F16, bool MASK>
__global__ __launch_bounds__(256) void k_gemm128(
        const _Float16* __restrict__ A, const _Float16* __restrict__ B,
        const float* __restrict__ bias, void* __restrict__ Cout,
        const unsigned char* __restrict__ flags, int Mstore, int N) {
    __shared__ __align__(16) _Float16 As[2][128 * 32];   // 16 KB (two k-halves)
    __shared__ __align__(16) _Float16 Bs[2][128 * 32];   // 16 KB
    int t = threadIdx.x;
    int w = t >> 6, L = t & 63;
    int wr = (w >> 1) * 64, wc = (w & 1) * 64;        // wave quadrant origin in tile
    int m0 = blockIdx.y * 128, n0 = blockIdx.x * 128; // n fastest: same-A blocks adjacent
    int lr = L & 15, lk = (L >> 4) * 8;

    f4_t acc[4][4] = {};

    auto stageH = [&](int k0, _Float16* Ad, _Float16* Bd) {
#pragma unroll
        for (int i = 0; i < 2; ++i) {                 // A: 512 16B chunks / 256 thr
            int c = t + 256 * i;
            __builtin_amdgcn_global_load_lds(
                (gbl_ptr_t)(A + (size_t)(m0 + (c >> 2)) * K + k0 + (c & 3) * 8),
                (lds_ptr_t)(Ad + c * 8), 16, 0, 0);
        }
#pragma unroll
        for (int i = 0; i < 2; ++i) {                 // B: 512 chunks
            int c = t + 256 * i;
            __builtin_amdgcn_global_load_lds(
                (gbl_ptr_t)(B + (size_t)(n0 + (c >> 2)) * K + k0 + (c & 3) * 8),
                (lds_ptr_t)(Bd + c * 8), 16, 0, 0);
        }
    };
    auto stage = [&](int k0) {                        // both halves: 8 loads/thread
        stageH(k0,      As[0], Bs[0]);
        stageH(k0 + 32, As[1], Bs[1]);
    };

    stage(0);
    constexpr int NS = K / 64;
#pragma unroll
    for (int s = 0; s < NS; ++s) {
        asm volatile("s_waitcnt vmcnt(0)" ::: "memory");   // own staging landed
        __syncthreads();                                   // ALL waves' staging landed
        // ---- sub-round 0 (k-half 0) ----
        h8_t af[4], bf[4];
#pragma unroll
        for (int i = 0; i < 4; ++i) af[i] = *(const h8_t*)&As[0][(wr + i * 16 + lr) * 32 + lk];
#pragma unroll
        for (int j = 0; j < 4; ++j) bf[j] = *(const h8_t*)&Bs[0][(wc + j * 16 + lr) * 32 + lk];
#pragma unroll
        for (int i = 0; i < 4; ++i)                        // MFMA h0 (auto-waitcnt on af/bf)
#pragma unroll
            for (int j = 0; j < 4; ++j)
                acc[i][j] = __builtin_amdgcn_mfma_f32_16x16x32_f16(af[i], bf[j], acc[i][j], 0, 0, 0);
        // ---- sub-round 1 (k-half 1): reads overlap h0's MFMAs ----
        h8_t af1[4], bf1[4];
#pragma unroll
        for (int i = 0; i < 4; ++i) af1[i] = *(const h8_t*)&As[1][(wr + i * 16 + lr) * 32 + lk];
#pragma unroll
        for (int j = 0; j < 4; ++j) bf1[j] = *(const h8_t*)&Bs[1][(wc + j * 16 + lr) * 32 + lk];
        asm volatile("s_waitcnt lgkmcnt(0)" ::: "memory"); // own LDS reads done
        __syncthreads();                                   // all waves done reading LDS
        if (s + 1 < NS) stage((s + 1) * 64);               // refill; overlaps MFMA h1
#pragma unroll
        for (int i = 0; i < 4; ++i)
#pragma unroll
            for (int j = 0; j < 4; ++j)
                acc[i][j] = __builtin_amdgcn_mfma_f32_16x16x32_f16(af1[i], bf1[j], acc[i][j], 0, 0, 0);
    }

    // epilogue: C/D layout col = L&15, row = (L>>4)*4 + r (R6 convention, verified)
    int lr4 = (L >> 4) * 4;
#pragma unroll
    for (int i = 0; i < 4; ++i)
#pragma unroll
        for (int r = 0; r < 4; ++r) {
            int row = m0 + wr + i * 16 + lr4 + r;
            float zm = 1.f;
            if constexpr (MASK) zm = flags[row] ? 0.f : 1.f;
#pragma unroll
            for (int j = 0; j < 4; ++j) {
                int col = n0 + wc + j * 16 + lr;
                float v = acc[i][j][r];
                if constexpr (HAS_BIAS) v += bias[col];
                if constexpr (RELU) v = v > 0.f ? v : 0.f;
                v *= zm;
                if constexpr (OUT_F16) {
                    ((_Float16*)Cout)[(size_t)row * N + col] = (_Float16)v;
                } else {
                    if (row < Mstore) ((float*)Cout)[(size_t)row * N + col] = v;
                }
            }
        }
}

extern "C" void kernel_launch(void* const* d_in, const int* in_sizes, int n_in,
                              void* d_out, int out_size, void* d_ws, size_t ws_size,
                              hipStream_t stream) {
    const float* x       = (const float*)d_in[0];
    const int*   ei      = (const int*)d_in[1];
    const int*   ea      = (const int*)d_in[2];
    const int*   mask    = (const int*)d_in[3];
    const float* prelu_a = (const float*)d_in[4];
    const float* W_enc   = (const float*)d_in[5];
    const float* E1      = (const float*)d_in[6];
    const float* E2      = (const float*)d_in[7];
    const float* W1      = (const float*)d_in[8];
    const float* b1      = (const float*)d_in[9];
    const float* W2      = (const float*)d_in[10];
    const float* b2      = (const float*)d_in[11];
    float*       out     = (float*)d_out;

    int N  = in_sizes[0] / HIDDEN;           // 20000
    int E  = in_sizes[1] / 2;                // 320000
    int NM = in_sizes[3];                    // 2000
    int Mpad = ((N + 127) / 128) * 128;      // 20096 (multiple of 128)

    char* ws = (char*)d_ws;
    size_t off = 0;
    _Float16* xh    = (_Float16*)(ws + off); off += (size_t)Mpad * HIDDEN * 2;
    _Float16* XEh   = (_Float16*)(ws + off); off += (size_t)Mpad * HIDDEN * 2;
    _Float16* AGh   = (_Float16*)(ws + off); off += (size_t)Mpad * HIDDEN * 2;
    _Float16* Hh    = (_Float16*)(ws + off); off += (size_t)Mpad * 2 * HIDDEN * 2;
    _Float16* Whenc = (_Float16*)(ws + off); off += (size_t)HIDDEN * HIDDEN * 2;
    _Float16* Wh1   = (_Float16*)(ws + off); off += (size_t)2 * HIDDEN * HIDDEN * 2;
    _Float16* Wh2   = (_Float16*)(ws + off); off += (size_t)HIDDEN * 2 * HIDDEN * 2;
    int* cnt        = (int*)(ws + off);      off += (size_t)N * 4;
    unsigned char* flags = (unsigned char*)(ws + off); off += (size_t)Mpad;
    off = (off + 15) & ~(size_t)15;
    int* csr        = (int*)(ws + off);      off += (size_t)N * CAP * 4;

    hipMemsetAsync(cnt, 0, (size_t)N * 4 + (size_t)Mpad, stream);   // cnt + flags

    int nb_x    = (Mpad * HIDDEN / 4 + 255) / 256;   // 5024
    int nb_fill = (E + 255) / 256;                   // 1250
    int wtot4   = (HIDDEN * HIDDEN + 2 * HIDDEN * HIDDEN + HIDDEN * 2 * HIDDEN) / 4;
    int nb_w    = (wtot4 + 255) / 256;               // 320
    int nb_m    = (NM + 255) / 256;                  // 8
    k_prep<<<nb_x + nb_fill + nb_w + nb_m, 256, 0, stream>>>(
        x, xh, prelu_a, N, Mpad, nb_x,
        ei, ea, E, cnt, csr, nb_fill,
        W_enc, W1, W2, Whenc, Wh1, Wh2, nb_w,
        mask, flags, NM);

    // GEMM1: XE = (prelu(x)@W_enc^T), masked rows zeroed. 128x128 tiles -> 2x157.
    dim3 g1(HIDDEN / 128, Mpad / 128);
    k_gemm128<HIDDEN, false, false, true, true><<<g1, 256, 0, stream>>>(
        xh, Whenc, nullptr, XEh, flags, N, HIDDEN);

    k_aggregate<<<(Mpad + 3) / 4, 256, 0, stream>>>(XEh, E1, E2, cnt, csr, AGh, N, Mpad);

    // GEMM2: H = relu(AG@W1^T + b1). 128x128 tiles -> 4x157.
    dim3 g2(2 * HIDDEN / 128, Mpad / 128);
    k_gemm128<HIDDEN, true, true, true, false><<<g2, 256, 0, stream>>>(
        AGh, Wh1, b1, Hh, nullptr, N, 2 * HIDDEN);

    // GEMM3: out = H@W2^T + b2 (f32). 128x128 tiles -> 2x157.
    dim3 g3(HIDDEN / 128, Mpad / 128);
    k_gemm128<2 * HIDDEN, false, true, false, false><<<g3, 256, 0, stream>>>(
        Hh, Wh2, b2, out, nullptr, N, HIDDEN);
}